// Round 3
// baseline (298.744 us; speedup 1.0000x reference)
//
#include <hip/hip_runtime.h>
#include <hip/hip_bf16.h>
#include <stdint.h>

#define D_IN   2048
#define D_SAE  32768
#define K_NNZ  64

#define SLICE_COLS 32
#define N_SLICES   (D_IN / SLICE_COLS)   // 64
#define N_XCD      8
#define ROWS_PER_BLOCK 64

typedef float vfloat4 __attribute__((ext_vector_type(4)));  // native vec for nontemporal
typedef int   vint4   __attribute__((ext_vector_type(4)));

static __device__ __forceinline__ uint16_t bf16_bits(float x) {
  __hip_bfloat16 h = __float2bfloat16(x);
  return *reinterpret_cast<uint16_t*>(&h);
}

// ---------------------------------------------------------------------------
// Dedup precompute: scatter .set = last-write-wins. v_clean[r][k] = 0 if any
// k' > k shares idx. One wave per row; runs once.
// ---------------------------------------------------------------------------
__global__ __launch_bounds__(64) void dedup_values(
    const int* __restrict__ indices, const float* __restrict__ values,
    float* __restrict__ v_clean) {
  __shared__ int si[K_NNZ];
  const int r = blockIdx.x;
  const int k = threadIdx.x;
  const int my = indices[(size_t)r * K_NNZ + k];
  si[k] = my;
  __syncthreads();
  float v = values[(size_t)r * K_NNZ + k];
  for (int k2 = k + 1; k2 < K_NNZ; ++k2) {
    if (si[k2] == my) { v = 0.0f; break; }
  }
  v_clean[(size_t)r * K_NNZ + k] = v;
}

// ---------------------------------------------------------------------------
// Transpose: W (2048 x 32768) fp32 -> WT bf16. Tile 64(d) x 256(s); reads are
// full 1KB contiguous spans per W row, LDS XOR-swizzled chunk layout.
// v2b (main path): SLICE-BLOCKED output WT_b[slice][row][cw], slice=col/32.
// Each 32-col slice is a contiguous 2MB region (half an XCD L2).
// At 384MB of HBM traffic this kernel is already at its BW floor (~60us).
// ---------------------------------------------------------------------------
#define TP_D 64
#define TP_S 256

static __device__ __forceinline__ int sw_idx(int r, int c) {
  return (((c >> 2) ^ ((r >> 3) & 7)) << 2) + (c & 3);
}

__global__ __launch_bounds__(256) void transpose_to_bf16_v2b(
    const float* __restrict__ W, __hip_bfloat16* __restrict__ WT) {
  __shared__ float tile[TP_D][TP_S];
  const int s0 = blockIdx.x * TP_S;
  const int d0 = blockIdx.y * TP_D;
  const int tid = threadIdx.x;
  const int w = tid >> 6, l = tid & 63;

#pragma unroll
  for (int i = 0; i < 16; ++i) {
    const int r = w * 16 + i;
    const float4 v = *reinterpret_cast<const float4*>(
        &W[(size_t)(d0 + r) * D_SAE + s0 + l * 4]);
    const int p = l ^ ((r >> 3) & 7);   // chunk swizzle
    *reinterpret_cast<float4*>(&tile[r][p << 2]) = v;
  }
  __syncthreads();

  const int a = l & 7;
  const int sub = l >> 3;
#pragma unroll
  for (int i = 0; i < 8; ++i) {
    const int sl = w * 64 + i * 8 + sub;
    uint32_t u[4];
#pragma unroll
    for (int jj = 0; jj < 4; ++jj) {
      const float f0 = tile[a * 8 + 2 * jj][sw_idx(a * 8 + 2 * jj, sl)];
      const float f1 = tile[a * 8 + 2 * jj + 1][sw_idx(a * 8 + 2 * jj + 1, sl)];
      u[jj] = (uint32_t)bf16_bits(f0) | ((uint32_t)bf16_bits(f1) << 16);
    }
    const int d = d0 + a * 8;            // global col of this 8-col chunk
    const int slice = d >> 5;            // 32-col slice id
    const int cw = d & 31;               // col within slice (0,8,16,24)
    *reinterpret_cast<uint4*>(
        &WT[((size_t)slice * D_SAE + (size_t)(s0 + sl)) * SLICE_COLS + cw]) =
        *reinterpret_cast<uint4*>(u);
  }
}

// Row-major variant kept for the fallback decode path.
__global__ __launch_bounds__(256) void transpose_to_bf16_v2(
    const float* __restrict__ W, __hip_bfloat16* __restrict__ WT) {
  __shared__ float tile[TP_D][TP_S];
  const int s0 = blockIdx.x * TP_S;
  const int d0 = blockIdx.y * TP_D;
  const int tid = threadIdx.x;
  const int w = tid >> 6, l = tid & 63;
#pragma unroll
  for (int i = 0; i < 16; ++i) {
    const int r = w * 16 + i;
    const float4 v = *reinterpret_cast<const float4*>(
        &W[(size_t)(d0 + r) * D_SAE + s0 + l * 4]);
    const int p = l ^ ((r >> 3) & 7);
    *reinterpret_cast<float4*>(&tile[r][p << 2]) = v;
  }
  __syncthreads();
  const int a = l & 7;
  const int sub = l >> 3;
#pragma unroll
  for (int i = 0; i < 8; ++i) {
    const int sl = w * 64 + i * 8 + sub;
    uint32_t u[4];
#pragma unroll
    for (int jj = 0; jj < 4; ++jj) {
      const float f0 = tile[a * 8 + 2 * jj][sw_idx(a * 8 + 2 * jj, sl)];
      const float f1 = tile[a * 8 + 2 * jj + 1][sw_idx(a * 8 + 2 * jj + 1, sl)];
      u[jj] = (uint32_t)bf16_bits(f0) | ((uint32_t)bf16_bits(f1) << 16);
    }
    *reinterpret_cast<uint4*>(&WT[(size_t)(s0 + sl) * D_IN + d0 + a * 8]) =
        *reinterpret_cast<uint4*>(u);
  }
}

// ---------------------------------------------------------------------------
// Decode v6: concurrency-forced gather pipeline.
// Round-2 evidence: VGPR=44 -> compiler sank each gather next to its consumer
// (~2 in flight); decode was L2-latency bound at ~28% of the L2 gather rate.
// This version pins the schedule:
//   * idx prefetched TWO iterations ahead into registers (gather issue never
//     waits on LDS latency); vals read from LDS during consume (their latency
//     hides under the gathers' vmcnt wait).
//   * loop body: consume(t) -> issue 8 gathers(t+1) -> prefetch idx(t+2)
//     -> sched_barrier(0) -> reduce+store(t).  The barrier forbids sinking
//     the loads below the ~200cy shuffle-reduce chain, so 8x64B stays in
//     flight per wave across it (20 waves/CU -> ~10KB outstanding per CU,
//     enough to saturate the L2/TA gather path).
//   * butterfly reduce-scatter (8 shfl + 8 add per row), coalesced 1-float
//     stores from lanes 0..31 (proven in v5).
// Est. VGPR ~87 (G 32 + idx 16 + acc 16 + vals 8 + addr/temps) under the
// 102 budget of __launch_bounds__(256,5); LDS 32KB -> 5 blocks/CU.
// ---------------------------------------------------------------------------
static __device__ __forceinline__ void consume8(float (&acc)[8], const uint4 wv,
                                                const float v) {
#pragma unroll
  for (int j = 0; j < 4; ++j) {
    const uint32_t u = (&wv.x)[j];
    acc[2 * j + 0] = fmaf(v, __uint_as_float(u << 16), acc[2 * j + 0]);
    acc[2 * j + 1] = fmaf(v, __uint_as_float(u & 0xffff0000u), acc[2 * j + 1]);
  }
}

static __device__ __forceinline__ float reduce_scatter32(float (&acc)[8],
                                                         const int rb0,
                                                         const int rb1,
                                                         const int rb2) {
  float t4[4];
#pragma unroll
  for (int j = 0; j < 4; ++j) {
    const float send = rb0 ? acc[j] : acc[j + 4];
    const float keep = rb0 ? acc[j + 4] : acc[j];
    t4[j] = keep + __shfl_xor(send, 4, 64);
  }
  float t2[2];
#pragma unroll
  for (int j = 0; j < 2; ++j) {
    const float send = rb1 ? t4[j] : t4[j + 2];
    const float keep = rb1 ? t4[j + 2] : t4[j];
    t2[j] = keep + __shfl_xor(send, 8, 64);
  }
  const float send = rb2 ? t2[0] : t2[1];
  const float keep = rb2 ? t2[1] : t2[0];
  const float t1 = keep + __shfl_xor(send, 16, 64);
  return t1 + __shfl_xor(t1, 32, 64);
}

__global__ __launch_bounds__(256, 5) void sae_decode_l6(
    const int* __restrict__ indices, const float* __restrict__ v_clean,
    const __hip_bfloat16* __restrict__ WT, const float* __restrict__ bias,
    float* __restrict__ out) {
  const int m = blockIdx.x & 7;                  // XCD pin
  const int rowchunk = blockIdx.x >> 3;
  const int slice = blockIdx.y * N_XCD + m;      // 0..63
  const int col0 = slice * SLICE_COLS;
  const int r0 = rowchunk * ROWS_PER_BLOCK;
  const int tid = threadIdx.x;
  const int w = tid >> 6, l = tid & 63;

  __shared__ int   s_idx[ROWS_PER_BLOCK * K_NNZ];   // 16 KB
  __shared__ float s_val[ROWS_PER_BLOCK * K_NNZ];   // 16 KB

  {  // stage 64 rows of idx/val: nontemporal b128 (protect resident L2 slice)
    const vint4*   gi = reinterpret_cast<const vint4*>(&indices[(size_t)r0 * K_NNZ]);
    const vfloat4* gv = reinterpret_cast<const vfloat4*>(&v_clean[(size_t)r0 * K_NNZ]);
#pragma unroll
    for (int i = 0; i < 4; ++i) {
      const int e = i * 256 + tid;
      reinterpret_cast<vint4*>(s_idx)[e]   = __builtin_nontemporal_load(&gi[e]);
      reinterpret_cast<vfloat4*>(s_val)[e] = __builtin_nontemporal_load(&gv[e]);
    }
  }
  __syncthreads();

  const int c = l & 3;                   // 16B chunk 0..3
  const int kg = l >> 2;                 // k-group 0..15
  const __hip_bfloat16* wbase =
      WT + (size_t)slice * ((size_t)D_SAE * SLICE_COLS) + c * 8;

  const int rb0 = kg & 1, rb1 = (kg >> 1) & 1, rb2 = (kg >> 2) & 1;
  const int mycol = c * 8 + rb0 * 4 + rb1 * 2 + rb2;   // bijective over 32
  const float mybias = bias[col0 + mycol];

  // Pipeline registers: G = gathers in flight for iteration t;
  // IA/IB[phase] = idx prefetched for iterations t+1 (issue) and t+2 (read).
  int IA[2][4], IB[2][4];
  uint4 G[8];

  // prologue: idx(0), gathers(0), idx(1)
#pragma unroll
  for (int s = 0; s < 4; ++s) {
    IA[0][s] = s_idx[(w + 0) * K_NNZ + s * 16 + kg];
    IB[0][s] = s_idx[(w + 4) * K_NNZ + s * 16 + kg];
  }
#pragma unroll
  for (int s = 0; s < 4; ++s) {
    G[s]     = *reinterpret_cast<const uint4*>(&wbase[(size_t)IA[0][s] * SLICE_COLS]);
    G[4 + s] = *reinterpret_cast<const uint4*>(&wbase[(size_t)IB[0][s] * SLICE_COLS]);
  }
#pragma unroll
  for (int s = 0; s < 4; ++s) {
    IA[1][s] = s_idx[(w + 8)  * K_NNZ + s * 16 + kg];
    IB[1][s] = s_idx[(w + 12) * K_NNZ + s * 16 + kg];
  }

#pragma unroll
  for (int t = 0; t < 8; ++t) {          // rows rA = w+8t, rB = rA+4
    const int rA = w + 8 * t;
    const int rB = rA + 4;

    // vals for this iteration (broadcast LDS reads; latency hides under the
    // vmcnt wait for G)
    float vA[4], vB[4];
#pragma unroll
    for (int s = 0; s < 4; ++s) {
      vA[s] = s_val[rA * K_NNZ + s * 16 + kg];
      vB[s] = s_val[rB * K_NNZ + s * 16 + kg];
    }

    float accA[8] = {0.f, 0.f, 0.f, 0.f, 0.f, 0.f, 0.f, 0.f};
    float accB[8] = {0.f, 0.f, 0.f, 0.f, 0.f, 0.f, 0.f, 0.f};
#pragma unroll
    for (int s = 0; s < 4; ++s) consume8(accA, G[s], vA[s]);
#pragma unroll
    for (int s = 0; s < 4; ++s) consume8(accB, G[4 + s], vB[s]);

    // issue next iteration's 8 gathers (idx already in registers)
    if (t < 7) {
#pragma unroll
      for (int s = 0; s < 4; ++s) {
        G[s]     = *reinterpret_cast<const uint4*>(
            &wbase[(size_t)IA[(t + 1) & 1][s] * SLICE_COLS]);
        G[4 + s] = *reinterpret_cast<const uint4*>(
            &wbase[(size_t)IB[(t + 1) & 1][s] * SLICE_COLS]);
      }
    }
    // prefetch idx for t+2 into the phase slot just consumed
    if (t < 6) {
      const int rA2 = w + 8 * (t + 2);
#pragma unroll
      for (int s = 0; s < 4; ++s) {
        IA[t & 1][s] = s_idx[rA2 * K_NNZ + s * 16 + kg];
        IB[t & 1][s] = s_idx[(rA2 + 4) * K_NNZ + s * 16 + kg];
      }
    }
    // pin: the 8 gathers above may NOT sink below the reduce chain
    __builtin_amdgcn_sched_barrier(0);

    const float sA = reduce_scatter32(accA, rb0, rb1, rb2);
    const float sB = reduce_scatter32(accB, rb0, rb1, rb2);
    if (l < 32) {
      __builtin_nontemporal_store(
          sA + mybias, &out[(size_t)(r0 + rA) * D_IN + col0 + mycol]);
      __builtin_nontemporal_store(
          sB + mybias, &out[(size_t)(r0 + rB) * D_IN + col0 + mycol]);
    }
  }
}

// ---------------------------------------------------------------------------
// Fallback A (ws fits WT only): R1's proven decode (in-kernel dedup,
// full-row blocks; uses row-major WT).
// ---------------------------------------------------------------------------
__global__ __launch_bounds__(256) void sae_decode_r1(
    const int* __restrict__ indices, const float* __restrict__ values,
    const __hip_bfloat16* __restrict__ WT, const float* __restrict__ bias,
    float* __restrict__ out) {
  const int row = blockIdx.x;
  const int tid = threadIdx.x;

  __shared__ int   s_idx[K_NNZ];
  __shared__ float s_val[K_NNZ];
  if (tid < K_NNZ) {
    s_idx[tid] = indices[(size_t)row * K_NNZ + tid];
    s_val[tid] = values[(size_t)row * K_NNZ + tid];
  }
  __syncthreads();
  if (tid < K_NNZ) {
    const int my = s_idx[tid];
    for (int k2 = tid + 1; k2 < K_NNZ; ++k2) {
      if (s_idx[k2] == my) { s_val[tid] = 0.0f; break; }
    }
  }
  __syncthreads();

  const int d0 = tid * 8;
  float acc[8];
  {
    const float4 b0 = *reinterpret_cast<const float4*>(&bias[d0]);
    const float4 b1 = *reinterpret_cast<const float4*>(&bias[d0 + 4]);
    acc[0] = b0.x; acc[1] = b0.y; acc[2] = b0.z; acc[3] = b0.w;
    acc[4] = b1.x; acc[5] = b1.y; acc[6] = b1.z; acc[7] = b1.w;
  }
#pragma unroll 4
  for (int k = 0; k < K_NNZ; ++k) {
    const float v = s_val[k];
    const int idx = s_idx[k];
    const uint4 wv = *reinterpret_cast<const uint4*>(
        &WT[(size_t)idx * D_IN + d0]);
#pragma unroll
    for (int j = 0; j < 4; ++j) {
      const uint32_t u = (&wv.x)[j];
      const float lo = __uint_as_float(u << 16);
      const float hi = __uint_as_float(u & 0xffff0000u);
      acc[2 * j + 0] = fmaf(v, lo, acc[2 * j + 0]);
      acc[2 * j + 1] = fmaf(v, hi, acc[2 * j + 1]);
    }
  }
  float4* o = reinterpret_cast<float4*>(&out[(size_t)row * D_IN + d0]);
  o[0] = make_float4(acc[0], acc[1], acc[2], acc[3]);
  o[1] = make_float4(acc[4], acc[5], acc[6], acc[7]);
}

// ---------------------------------------------------------------------------
// Fallback B (tiny ws): direct fp32 gather. Insurance only.
// ---------------------------------------------------------------------------
__global__ __launch_bounds__(256) void sae_decode_direct(
    const int* __restrict__ indices, const float* __restrict__ values,
    const float* __restrict__ W, const float* __restrict__ bias,
    float* __restrict__ out) {
  const int row = blockIdx.x;
  const int tid = threadIdx.x;
  __shared__ int   s_idx[K_NNZ];
  __shared__ float s_val[K_NNZ];
  if (tid < K_NNZ) {
    s_idx[tid] = indices[(size_t)row * K_NNZ + tid];
    s_val[tid] = values[(size_t)row * K_NNZ + tid];
  }
  __syncthreads();
  if (tid < K_NNZ) {
    const int my = s_idx[tid];
    for (int k2 = tid + 1; k2 < K_NNZ; ++k2) {
      if (s_idx[k2] == my) { s_val[tid] = 0.0f; break; }
    }
  }
  __syncthreads();
  const int d0 = tid * 8;
  float acc[8];
#pragma unroll
  for (int j = 0; j < 8; ++j) acc[j] = bias[d0 + j];
  for (int k = 0; k < K_NNZ; ++k) {
    const float v = s_val[k];
    const int idx = s_idx[k];
#pragma unroll
    for (int j = 0; j < 8; ++j) {
      acc[j] = fmaf(v, W[(size_t)(d0 + j) * D_SAE + idx], acc[j]);
    }
  }
  float4* o = reinterpret_cast<float4*>(&out[(size_t)row * D_IN + d0]);
  o[0] = make_float4(acc[0], acc[1], acc[2], acc[3]);
  o[1] = make_float4(acc[4], acc[5], acc[6], acc[7]);
}

extern "C" void kernel_launch(void* const* d_in, const int* in_sizes, int n_in,
                              void* d_out, int out_size, void* d_ws, size_t ws_size,
                              hipStream_t stream) {
  const int*   indices = (const int*)d_in[0];
  const float* values  = (const float*)d_in[1];
  const float* W       = (const float*)d_in[2];
  const float* bias    = (const float*)d_in[3];
  float* out = (float*)d_out;

  const int n_rows = in_sizes[0] / K_NNZ;  // 8192
  const size_t wt_bytes = (size_t)D_SAE * D_IN * sizeof(__hip_bfloat16);
  const size_t vc_bytes = (size_t)n_rows * K_NNZ * sizeof(float);

  if (ws_size >= wt_bytes + vc_bytes && (n_rows % ROWS_PER_BLOCK) == 0) {
    __hip_bfloat16* WT = (__hip_bfloat16*)d_ws;   // slice-blocked layout
    float* v_clean = (float*)((char*)d_ws + wt_bytes);
    transpose_to_bf16_v2b<<<dim3(D_SAE / TP_S, D_IN / TP_D), 256, 0, stream>>>(W, WT);
    dedup_values<<<n_rows, 64, 0, stream>>>(indices, values, v_clean);
    dim3 g2(N_XCD * (n_rows / ROWS_PER_BLOCK), N_SLICES / N_XCD);  // (1024, 8)
    sae_decode_l6<<<g2, 256, 0, stream>>>(indices, v_clean, WT, bias, out);
  } else if (ws_size >= wt_bytes) {
    __hip_bfloat16* WT = (__hip_bfloat16*)d_ws;   // row-major layout
    transpose_to_bf16_v2<<<dim3(D_SAE / TP_S, D_IN / TP_D), 256, 0, stream>>>(W, WT);
    sae_decode_r1<<<n_rows, 256, 0, stream>>>(indices, values, WT, bias, out);
  } else {
    sae_decode_direct<<<n_rows, 256, 0, stream>>>(indices, values, W, bias, out);
  }
}

// Round 4
// 271.302 us; speedup vs baseline: 1.1011x; 1.1011x over previous
//
#include <hip/hip_runtime.h>
#include <hip/hip_bf16.h>
#include <stdint.h>

#define D_IN   2048
#define D_SAE  32768
#define K_NNZ  64

#define SLICE_COLS 32
#define N_SLICES   (D_IN / SLICE_COLS)   // 64
#define N_XCD      8
#define ROWS_PER_BLOCK 64

typedef float vfloat4 __attribute__((ext_vector_type(4)));  // native vec for nontemporal
typedef int   vint4   __attribute__((ext_vector_type(4)));

static __device__ __forceinline__ uint16_t bf16_bits(float x) {
  __hip_bfloat16 h = __float2bfloat16(x);
  return *reinterpret_cast<uint16_t*>(&h);
}

// ---------------------------------------------------------------------------
// Dedup precompute: scatter .set = last-write-wins. v_clean[r][k] = 0 if any
// k' > k shares idx. One wave per row; runs once.
// ---------------------------------------------------------------------------
__global__ __launch_bounds__(64) void dedup_values(
    const int* __restrict__ indices, const float* __restrict__ values,
    float* __restrict__ v_clean) {
  __shared__ int si[K_NNZ];
  const int r = blockIdx.x;
  const int k = threadIdx.x;
  const int my = indices[(size_t)r * K_NNZ + k];
  si[k] = my;
  __syncthreads();
  float v = values[(size_t)r * K_NNZ + k];
  for (int k2 = k + 1; k2 < K_NNZ; ++k2) {
    if (si[k2] == my) { v = 0.0f; break; }
  }
  v_clean[(size_t)r * K_NNZ + k] = v;
}

// ---------------------------------------------------------------------------
// Transpose: W (2048 x 32768) fp32 -> WT bf16. Tile 64(d) x 256(s); reads are
// full 1KB contiguous spans per W row, LDS XOR-swizzled chunk layout.
// v2b (main path): SLICE-BLOCKED output WT_b[slice][row][cw], slice=col/32.
// Each 32-col slice is a contiguous 2MB region (half an XCD L2).
// At 384MB of HBM traffic this kernel is already at its BW floor (~60us).
// ---------------------------------------------------------------------------
#define TP_D 64
#define TP_S 256

static __device__ __forceinline__ int sw_idx(int r, int c) {
  return (((c >> 2) ^ ((r >> 3) & 7)) << 2) + (c & 3);
}

__global__ __launch_bounds__(256) void transpose_to_bf16_v2b(
    const float* __restrict__ W, __hip_bfloat16* __restrict__ WT) {
  __shared__ float tile[TP_D][TP_S];
  const int s0 = blockIdx.x * TP_S;
  const int d0 = blockIdx.y * TP_D;
  const int tid = threadIdx.x;
  const int w = tid >> 6, l = tid & 63;

#pragma unroll
  for (int i = 0; i < 16; ++i) {
    const int r = w * 16 + i;
    const float4 v = *reinterpret_cast<const float4*>(
        &W[(size_t)(d0 + r) * D_SAE + s0 + l * 4]);
    const int p = l ^ ((r >> 3) & 7);   // chunk swizzle
    *reinterpret_cast<float4*>(&tile[r][p << 2]) = v;
  }
  __syncthreads();

  const int a = l & 7;
  const int sub = l >> 3;
#pragma unroll
  for (int i = 0; i < 8; ++i) {
    const int sl = w * 64 + i * 8 + sub;
    uint32_t u[4];
#pragma unroll
    for (int jj = 0; jj < 4; ++jj) {
      const float f0 = tile[a * 8 + 2 * jj][sw_idx(a * 8 + 2 * jj, sl)];
      const float f1 = tile[a * 8 + 2 * jj + 1][sw_idx(a * 8 + 2 * jj + 1, sl)];
      u[jj] = (uint32_t)bf16_bits(f0) | ((uint32_t)bf16_bits(f1) << 16);
    }
    const int d = d0 + a * 8;            // global col of this 8-col chunk
    const int slice = d >> 5;            // 32-col slice id
    const int cw = d & 31;               // col within slice (0,8,16,24)
    *reinterpret_cast<uint4*>(
        &WT[((size_t)slice * D_SAE + (size_t)(s0 + sl)) * SLICE_COLS + cw]) =
        *reinterpret_cast<uint4*>(u);
  }
}

// Row-major variant kept for the fallback decode path.
__global__ __launch_bounds__(256) void transpose_to_bf16_v2(
    const float* __restrict__ W, __hip_bfloat16* __restrict__ WT) {
  __shared__ float tile[TP_D][TP_S];
  const int s0 = blockIdx.x * TP_S;
  const int d0 = blockIdx.y * TP_D;
  const int tid = threadIdx.x;
  const int w = tid >> 6, l = tid & 63;
#pragma unroll
  for (int i = 0; i < 16; ++i) {
    const int r = w * 16 + i;
    const float4 v = *reinterpret_cast<const float4*>(
        &W[(size_t)(d0 + r) * D_SAE + s0 + l * 4]);
    const int p = l ^ ((r >> 3) & 7);
    *reinterpret_cast<float4*>(&tile[r][p << 2]) = v;
  }
  __syncthreads();
  const int a = l & 7;
  const int sub = l >> 3;
#pragma unroll
  for (int i = 0; i < 8; ++i) {
    const int sl = w * 64 + i * 8 + sub;
    uint32_t u[4];
#pragma unroll
    for (int jj = 0; jj < 4; ++jj) {
      const float f0 = tile[a * 8 + 2 * jj][sw_idx(a * 8 + 2 * jj, sl)];
      const float f1 = tile[a * 8 + 2 * jj + 1][sw_idx(a * 8 + 2 * jj + 1, sl)];
      u[jj] = (uint32_t)bf16_bits(f0) | ((uint32_t)bf16_bits(f1) << 16);
    }
    *reinterpret_cast<uint4*>(&WT[(size_t)(s0 + sl) * D_IN + d0 + a * 8]) =
        *reinterpret_cast<uint4*>(u);
  }
}

// ---------------------------------------------------------------------------
// Decode v7: TLP-maximized gather (no LDS, no per-wave pipeline).
// Rounds 2-3 proved per-wave ILP forcing fails (compiler sinks loads at
// VGPR=48; forcing it spills to scratch: WRITE 65->106MB, dur worse).  The
// remaining lever is WAVES: LDS staging (32KB) was capping us at 5 blocks/CU
// (~13 waves measured).  idx/val are only 4MB total and each element is
// reused by the 8 slice-blocks of its XCD -> L2 serves these reads without
// staging.  Dropping LDS entirely:
//   * no __syncthreads, no staging instructions,
//   * occupancy cap moves to VGPR (~50 in this v5-style body) -> ~8
//     waves/SIMD = ~32 waves/CU, 2.4x current -> in-flight gather lines/CU
//     rises past the latency-BW product of the L2 path for the first time.
// Proven pieces kept: slice-blocked WT (2MB/slice, FETCH near-ideal),
// XCD-pinned dispatch, butterfly reduce-scatter, coalesced 1-float stores.
// Lane map: c = l&3 (16B chunk), kg = l>>2 (k-group).
// ---------------------------------------------------------------------------
static __device__ __forceinline__ void consume8(float (&acc)[8], const uint4 wv,
                                                const float v) {
#pragma unroll
  for (int j = 0; j < 4; ++j) {
    const uint32_t u = (&wv.x)[j];
    acc[2 * j + 0] = fmaf(v, __uint_as_float(u << 16), acc[2 * j + 0]);
    acc[2 * j + 1] = fmaf(v, __uint_as_float(u & 0xffff0000u), acc[2 * j + 1]);
  }
}

static __device__ __forceinline__ float reduce_scatter32(float (&acc)[8],
                                                         const int rb0,
                                                         const int rb1,
                                                         const int rb2) {
  float t4[4];
#pragma unroll
  for (int j = 0; j < 4; ++j) {
    const float send = rb0 ? acc[j] : acc[j + 4];
    const float keep = rb0 ? acc[j + 4] : acc[j];
    t4[j] = keep + __shfl_xor(send, 4, 64);
  }
  float t2[2];
#pragma unroll
  for (int j = 0; j < 2; ++j) {
    const float send = rb1 ? t4[j] : t4[j + 2];
    const float keep = rb1 ? t4[j + 2] : t4[j];
    t2[j] = keep + __shfl_xor(send, 8, 64);
  }
  const float send = rb2 ? t2[0] : t2[1];
  const float keep = rb2 ? t2[1] : t2[0];
  const float t1 = keep + __shfl_xor(send, 16, 64);
  return t1 + __shfl_xor(t1, 32, 64);
}

__global__ __launch_bounds__(256) void sae_decode_l7(
    const int* __restrict__ indices, const float* __restrict__ v_clean,
    const __hip_bfloat16* __restrict__ WT, const float* __restrict__ bias,
    float* __restrict__ out) {
  const int m = blockIdx.x & 7;                  // XCD pin
  const int rowchunk = blockIdx.x >> 3;
  const int slice = blockIdx.y * N_XCD + m;      // 0..63
  const int col0 = slice * SLICE_COLS;
  const int r0 = rowchunk * ROWS_PER_BLOCK;
  const int tid = threadIdx.x;
  const int w = tid >> 6, l = tid & 63;

  const int c = l & 3;                   // 16B chunk 0..3
  const int kg = l >> 2;                 // k-group 0..15
  const __hip_bfloat16* wbase =
      WT + (size_t)slice * ((size_t)D_SAE * SLICE_COLS) + c * 8;

  const int rb0 = kg & 1, rb1 = (kg >> 1) & 1, rb2 = (kg >> 2) & 1;
  const int mycol = c * 8 + rb0 * 4 + rb1 * 2 + rb2;   // bijective over 32
  const float mybias = bias[col0 + mycol];

  for (int t = 0; t < 8; ++t) {          // rows rA = r0+w+8t, rB = rA+4
    const int rA = r0 + w + 8 * t;
    const int rB = rA + 4;
    const size_t bA = (size_t)rA * K_NNZ + kg;   // lane's k-offsets
    const size_t bB = (size_t)rB * K_NNZ + kg;

    // idx/val straight from global: 16 distinct words per instr, broadcast
    // across the 4 c-lanes; L2-resident (4MB total, 8x reuse per XCD).
    int iA[4], iB[4];
#pragma unroll
    for (int s = 0; s < 4; ++s) {
      iA[s] = indices[bA + s * 16];
      iB[s] = indices[bB + s * 16];
    }
    float vA[4], vB[4];
#pragma unroll
    for (int s = 0; s < 4; ++s) {
      vA[s] = v_clean[bA + s * 16];
      vB[s] = v_clean[bB + s * 16];
    }

    uint4 GA[4], GB[4];
#pragma unroll
    for (int s = 0; s < 4; ++s) {
      GA[s] = *reinterpret_cast<const uint4*>(&wbase[(size_t)iA[s] * SLICE_COLS]);
      GB[s] = *reinterpret_cast<const uint4*>(&wbase[(size_t)iB[s] * SLICE_COLS]);
    }

    float accA[8] = {0.f, 0.f, 0.f, 0.f, 0.f, 0.f, 0.f, 0.f};
    float accB[8] = {0.f, 0.f, 0.f, 0.f, 0.f, 0.f, 0.f, 0.f};
#pragma unroll
    for (int s = 0; s < 4; ++s) consume8(accA, GA[s], vA[s]);
#pragma unroll
    for (int s = 0; s < 4; ++s) consume8(accB, GB[s], vB[s]);

    const float sA = reduce_scatter32(accA, rb0, rb1, rb2);
    const float sB = reduce_scatter32(accB, rb0, rb1, rb2);
    if (l < 32) {
      __builtin_nontemporal_store(
          sA + mybias, &out[(size_t)rA * D_IN + col0 + mycol]);
      __builtin_nontemporal_store(
          sB + mybias, &out[(size_t)rB * D_IN + col0 + mycol]);
    }
  }
}

// ---------------------------------------------------------------------------
// Fallback A (ws fits WT only): R1's proven decode (in-kernel dedup,
// full-row blocks; uses row-major WT).
// ---------------------------------------------------------------------------
__global__ __launch_bounds__(256) void sae_decode_r1(
    const int* __restrict__ indices, const float* __restrict__ values,
    const __hip_bfloat16* __restrict__ WT, const float* __restrict__ bias,
    float* __restrict__ out) {
  const int row = blockIdx.x;
  const int tid = threadIdx.x;

  __shared__ int   s_idx[K_NNZ];
  __shared__ float s_val[K_NNZ];
  if (tid < K_NNZ) {
    s_idx[tid] = indices[(size_t)row * K_NNZ + tid];
    s_val[tid] = values[(size_t)row * K_NNZ + tid];
  }
  __syncthreads();
  if (tid < K_NNZ) {
    const int my = s_idx[tid];
    for (int k2 = tid + 1; k2 < K_NNZ; ++k2) {
      if (s_idx[k2] == my) { s_val[tid] = 0.0f; break; }
    }
  }
  __syncthreads();

  const int d0 = tid * 8;
  float acc[8];
  {
    const float4 b0 = *reinterpret_cast<const float4*>(&bias[d0]);
    const float4 b1 = *reinterpret_cast<const float4*>(&bias[d0 + 4]);
    acc[0] = b0.x; acc[1] = b0.y; acc[2] = b0.z; acc[3] = b0.w;
    acc[4] = b1.x; acc[5] = b1.y; acc[6] = b1.z; acc[7] = b1.w;
  }
#pragma unroll 4
  for (int k = 0; k < K_NNZ; ++k) {
    const float v = s_val[k];
    const int idx = s_idx[k];
    const uint4 wv = *reinterpret_cast<const uint4*>(
        &WT[(size_t)idx * D_IN + d0]);
#pragma unroll
    for (int j = 0; j < 4; ++j) {
      const uint32_t u = (&wv.x)[j];
      const float lo = __uint_as_float(u << 16);
      const float hi = __uint_as_float(u & 0xffff0000u);
      acc[2 * j + 0] = fmaf(v, lo, acc[2 * j + 0]);
      acc[2 * j + 1] = fmaf(v, hi, acc[2 * j + 1]);
    }
  }
  float4* o = reinterpret_cast<float4*>(&out[(size_t)row * D_IN + d0]);
  o[0] = make_float4(acc[0], acc[1], acc[2], acc[3]);
  o[1] = make_float4(acc[4], acc[5], acc[6], acc[7]);
}

// ---------------------------------------------------------------------------
// Fallback B (tiny ws): direct fp32 gather. Insurance only.
// ---------------------------------------------------------------------------
__global__ __launch_bounds__(256) void sae_decode_direct(
    const int* __restrict__ indices, const float* __restrict__ values,
    const float* __restrict__ W, const float* __restrict__ bias,
    float* __restrict__ out) {
  const int row = blockIdx.x;
  const int tid = threadIdx.x;
  __shared__ int   s_idx[K_NNZ];
  __shared__ float s_val[K_NNZ];
  if (tid < K_NNZ) {
    s_idx[tid] = indices[(size_t)row * K_NNZ + tid];
    s_val[tid] = values[(size_t)row * K_NNZ + tid];
  }
  __syncthreads();
  if (tid < K_NNZ) {
    const int my = s_idx[tid];
    for (int k2 = tid + 1; k2 < K_NNZ; ++k2) {
      if (s_idx[k2] == my) { s_val[tid] = 0.0f; break; }
    }
  }
  __syncthreads();
  const int d0 = tid * 8;
  float acc[8];
#pragma unroll
  for (int j = 0; j < 8; ++j) acc[j] = bias[d0 + j];
  for (int k = 0; k < K_NNZ; ++k) {
    const float v = s_val[k];
    const int idx = s_idx[k];
#pragma unroll
    for (int j = 0; j < 8; ++j) {
      acc[j] = fmaf(v, W[(size_t)(d0 + j) * D_SAE + idx], acc[j]);
    }
  }
  float4* o = reinterpret_cast<float4*>(&out[(size_t)row * D_IN + d0]);
  o[0] = make_float4(acc[0], acc[1], acc[2], acc[3]);
  o[1] = make_float4(acc[4], acc[5], acc[6], acc[7]);
}

extern "C" void kernel_launch(void* const* d_in, const int* in_sizes, int n_in,
                              void* d_out, int out_size, void* d_ws, size_t ws_size,
                              hipStream_t stream) {
  const int*   indices = (const int*)d_in[0];
  const float* values  = (const float*)d_in[1];
  const float* W       = (const float*)d_in[2];
  const float* bias    = (const float*)d_in[3];
  float* out = (float*)d_out;

  const int n_rows = in_sizes[0] / K_NNZ;  // 8192
  const size_t wt_bytes = (size_t)D_SAE * D_IN * sizeof(__hip_bfloat16);
  const size_t vc_bytes = (size_t)n_rows * K_NNZ * sizeof(float);

  if (ws_size >= wt_bytes + vc_bytes && (n_rows % ROWS_PER_BLOCK) == 0) {
    __hip_bfloat16* WT = (__hip_bfloat16*)d_ws;   // slice-blocked layout
    float* v_clean = (float*)((char*)d_ws + wt_bytes);
    transpose_to_bf16_v2b<<<dim3(D_SAE / TP_S, D_IN / TP_D), 256, 0, stream>>>(W, WT);
    dedup_values<<<n_rows, 64, 0, stream>>>(indices, values, v_clean);
    dim3 g2(N_XCD * (n_rows / ROWS_PER_BLOCK), N_SLICES / N_XCD);  // (1024, 8)
    sae_decode_l7<<<g2, 256, 0, stream>>>(indices, v_clean, WT, bias, out);
  } else if (ws_size >= wt_bytes) {
    __hip_bfloat16* WT = (__hip_bfloat16*)d_ws;   // row-major layout
    transpose_to_bf16_v2<<<dim3(D_SAE / TP_S, D_IN / TP_D), 256, 0, stream>>>(W, WT);
    sae_decode_r1<<<n_rows, 256, 0, stream>>>(indices, values, WT, bias, out);
  } else {
    sae_decode_direct<<<n_rows, 256, 0, stream>>>(indices, values, W, bias, out);
  }
}